// Round 12
// baseline (4036.314 us; speedup 1.0000x reference)
//
#include <hip/hip_runtime.h>
#include <hip/hip_bf16.h>

// B=64, S=2048, WIN=50, E=128, H=256, G=4H=1024.
#define B_ 64
#define S_ 2048
#define W_ 50
#define E_ 128
#define H_ 256
#define G_ 1024

typedef unsigned short u16;
typedef unsigned int u32;
typedef unsigned int v4u __attribute__((ext_vector_type(4)));

// Module-global scratch (BSS; d_ws untrusted).
__device__ int g_mode;                          // 0 = bf16 buffers, 1 = fp32 buffers
__device__ u16 g_WihT[E_ * G_];                 // [e][4u+q] = Wih[q*H+u][e]  (bf16)
__device__ u32 g_Wi8[G_ * 64];                  // [u][k][g]: u*256+j*4+g = pack4(Whh[g*256+u][4j..4j+3])
__device__ float g_wscale[G_];                  // per-column dequant: max|W[:,c]| /(127*127), c=4u+g
__device__ u16 g_xg[(size_t)B_ * S_ * G_];      // [b][s][1024] bf16, biases folded (validated)
__device__ float g_hs[(size_t)B_ * S_ * H_];    // [b][s][u] fp32 hidden states (for output head)

__device__ __forceinline__ float b2f(u16 u) {
    union { u32 i; float f; } v;
    v.i = ((u32)u) << 16;
    return v.f;
}
__device__ __forceinline__ u16 f2b(float f) {
    __hip_bfloat16 h = __float2bfloat16(f);
    return *reinterpret_cast<u16*>(&h);
}
__device__ __forceinline__ float ldin(int mode, const void* p, size_t i) {
    return mode ? ((const float*)p)[i] : b2f(((const u16*)p)[i]);
}
__device__ __forceinline__ float clamp30(float x) {
    return fminf(fmaxf(x, -30.0f), 30.0f);
}
__device__ __forceinline__ float sigmoidf_(float x) { return 1.0f / (1.0f + __expf(-x)); }
__device__ __forceinline__ float tanhf_(float x) {
    float e = __expf(2.0f * x);
    return 1.0f - 2.0f / (e + 1.0f);
}
__device__ __forceinline__ int dot4i8(u32 a, u32 b, int acc) {
#if __has_builtin(__builtin_amdgcn_sdot4)
    return __builtin_amdgcn_sdot4(a, b, acc, false);
#else
    acc += (int)(signed char)(a)       * (int)(signed char)(b);
    acc += (int)(signed char)(a >> 8)  * (int)(signed char)(b >> 8);
    acc += (int)(signed char)(a >> 16) * (int)(signed char)(b >> 16);
    acc += (int)(signed char)(a >> 24) * (int)(signed char)(b >> 24);
    return acc;
#endif
}

// ---------- K0: dtype sniffer (validated) ----------
__global__ void sniff_kernel(const u16* __restrict__ wemb) {
    int sane = 0;
    for (int i = 0; i < 2048; ++i) {
        int ex = (wemb[i] >> 7) & 0xFF;
        if (ex == 0 || (ex >= 96 && ex <= 143)) ++sane;
    }
    g_mode = (sane >= 1900) ? 0 : 1;
}

// ---------- K0b: Wih gate-interleaved transpose (for xg_kernel) ----------
__global__ __launch_bounds__(256) void transpose_wih(const void* __restrict__ src) {
    const int mode = g_mode;
    int i = blockIdx.x * 256 + threadIdx.x;          // i = e*G + 4u+q
    int e = i >> 10, r = i & 1023, u = r >> 2, q = r & 3;
    g_WihT[i] = f2b(ldin(mode, src, (size_t)((q << 15) + (u << 7) + e)));
}

// ---------- K0c: Whh -> int8, unit-major quad layout [u][j][g] (validated r11 compile) ----------
__global__ __launch_bounds__(256) void prep_wi8(const void* __restrict__ src) {
    const int mode = g_mode;
    int c = blockIdx.x * 256 + threadIdx.x;          // c = 4u+g, 0..1023
    int row = ((c & 3) << 8) + (c >> 2);             // gate*256 + unit (validated)
    const size_t base = (size_t)row * H_;
    float m = 0.0f;
    for (int k = 0; k < H_; ++k) m = fmaxf(m, fabsf(ldin(mode, src, base + k)));
    float inv = (m > 0.0f) ? 127.0f / m : 0.0f;
    g_wscale[c] = m / (127.0f * 127.0f);             // w-scale * h-scale(1/127)
    for (int j = 0; j < 64; ++j) {
        u32 pk = 0;
#pragma unroll
        for (int i = 0; i < 4; ++i) {
            int q = (int)rintf(ldin(mode, src, base + 4 * j + i) * inv);
            q = max(-127, min(127, q));
            pk |= ((u32)(q & 0xff)) << (8 * i);
        }
        g_Wi8[(size_t)(c >> 2) * 256 + j * 4 + (c & 3)] = pk;
    }
}

// ---------- K1: fused embedding + input projection (validated round 4) ----------
__global__ __launch_bounds__(256) void xg_kernel(const void* __restrict__ pw,
                                                 const void* __restrict__ Wemb,
                                                 const void* __restrict__ bemb,
                                                 const void* __restrict__ bih,
                                                 const void* __restrict__ bhh) {
    const int mode = g_mode;
    const int t = threadIdx.x;
    const int m0 = blockIdx.x * 16;
    __shared__ float pw16[16][W_ + 2];
    __shared__ float Wl[E_ * 51];
    __shared__ __align__(16) float erow[16][E_];

    for (int i = t; i < E_ * W_; i += 256) {
        int e = i / W_, w = i - e * W_;
        Wl[e * 51 + w] = ldin(mode, Wemb, i);
    }
    for (int i = t; i < 16 * W_; i += 256) {
        int r = i / W_, w = i - r * W_;
        pw16[r][w] = ldin(mode, pw, (size_t)(m0 + r) * W_ + w);
    }
    __syncthreads();

#pragma unroll
    for (int i = 0; i < 8; ++i) {
        int idx = i * 256 + t;
        int r = idx >> 7, e = idx & 127;
        float a = ldin(mode, bemb, e);
        const float* wr = &Wl[e * 51];
#pragma unroll
        for (int w = 0; w < W_; ++w) a = fmaf(pw16[r][w], wr[w], a);
        erow[r][e] = fmaxf(a, 0.0f);
    }
    __syncthreads();

    const int g0 = 4 * t;
    float acc[16][4];
    {
        float b0 = ldin(mode, bih, t) + ldin(mode, bhh, t);
        float b1 = ldin(mode, bih, H_ + t) + ldin(mode, bhh, H_ + t);
        float b2 = ldin(mode, bih, 2 * H_ + t) + ldin(mode, bhh, 2 * H_ + t);
        float b3 = ldin(mode, bih, 3 * H_ + t) + ldin(mode, bhh, 3 * H_ + t);
#pragma unroll
        for (int r = 0; r < 16; ++r) { acc[r][0] = b0; acc[r][1] = b1; acc[r][2] = b2; acc[r][3] = b3; }
    }
    for (int e = 0; e < E_; e += 4) {
        ushort4 w0 = *(const ushort4*)(g_WihT + (size_t)(e + 0) * G_ + g0);
        ushort4 w1 = *(const ushort4*)(g_WihT + (size_t)(e + 1) * G_ + g0);
        ushort4 w2 = *(const ushort4*)(g_WihT + (size_t)(e + 2) * G_ + g0);
        ushort4 w3 = *(const ushort4*)(g_WihT + (size_t)(e + 3) * G_ + g0);
        float f00 = b2f(w0.x), f01 = b2f(w0.y), f02 = b2f(w0.z), f03 = b2f(w0.w);
        float f10 = b2f(w1.x), f11 = b2f(w1.y), f12 = b2f(w1.z), f13 = b2f(w1.w);
        float f20 = b2f(w2.x), f21 = b2f(w2.y), f22 = b2f(w2.z), f23 = b2f(w2.w);
        float f30 = b2f(w3.x), f31 = b2f(w3.y), f32 = b2f(w3.z), f33 = b2f(w3.w);
#pragma unroll
        for (int r = 0; r < 16; ++r) {
            float4 ev = *(const float4*)&erow[r][e];
            acc[r][0] = fmaf(ev.x, f00, acc[r][0]); acc[r][1] = fmaf(ev.x, f01, acc[r][1]);
            acc[r][2] = fmaf(ev.x, f02, acc[r][2]); acc[r][3] = fmaf(ev.x, f03, acc[r][3]);
            acc[r][0] = fmaf(ev.y, f10, acc[r][0]); acc[r][1] = fmaf(ev.y, f11, acc[r][1]);
            acc[r][2] = fmaf(ev.y, f12, acc[r][2]); acc[r][3] = fmaf(ev.y, f13, acc[r][3]);
            acc[r][0] = fmaf(ev.z, f20, acc[r][0]); acc[r][1] = fmaf(ev.z, f21, acc[r][1]);
            acc[r][2] = fmaf(ev.z, f22, acc[r][2]); acc[r][3] = fmaf(ev.z, f23, acc[r][3]);
            acc[r][0] = fmaf(ev.w, f30, acc[r][0]); acc[r][1] = fmaf(ev.w, f31, acc[r][1]);
            acc[r][2] = fmaf(ev.w, f32, acc[r][2]); acc[r][3] = fmaf(ev.w, f33, acc[r][3]);
        }
    }
#pragma unroll
    for (int r = 0; r < 16; ++r) {
        ushort4 sv;
        sv.x = f2b(acc[r][0]); sv.y = f2b(acc[r][1]);
        sv.z = f2b(acc[r][2]); sv.w = f2b(acc[r][3]);
        *(ushort4*)(g_xg + (size_t)(m0 + r) * G_ + g0) = sv;
    }
}

// ---------- K2: recurrence, unit-per-thread (256 thr), 1 barrier/step ----------
// Thread t = hidden unit t, all 4 gates local. 64 weight quads in named v4u via asm;
// EVERY asm block ends with s_waitcnt vmcnt(0) (no in-flight regs the compiler could copy).
// h exchanged as packed i8 via double-buffered LDS; h streamed out as FP32 for the head.
__global__ __launch_bounds__(256)
__attribute__((amdgpu_waves_per_eu(1, 1)))
void lstm_unit(const void* __restrict__ h0, const void* __restrict__ c0) {
    const int mode = g_mode;
    const int t = threadIdx.x;
    const int b = blockIdx.x;

    __shared__ __align__(16) u32 h8[2][H_ / 4];  // double-buffered h (i8), 2x256 B

    v4u W00, W01, W02, W03, W04, W05, W06, W07, W08, W09, W10, W11, W12, W13, W14, W15;
    v4u W16, W17, W18, W19, W20, W21, W22, W23, W24, W25, W26, W27, W28, W29, W30, W31;
    v4u W32, W33, W34, W35, W36, W37, W38, W39, W40, W41, W42, W43, W44, W45, W46, W47;
    v4u W48, W49, W50, W51, W52, W53, W54, W55, W56, W57, W58, W59, W60, W61, W62, W63;
    {
        const u32* wp = g_Wi8 + (size_t)t * 256;
        asm volatile(
            "global_load_dwordx4 %0, %16, off\n\t"
            "global_load_dwordx4 %1, %16, off offset:16\n\t"
            "global_load_dwordx4 %2, %16, off offset:32\n\t"
            "global_load_dwordx4 %3, %16, off offset:48\n\t"
            "global_load_dwordx4 %4, %16, off offset:64\n\t"
            "global_load_dwordx4 %5, %16, off offset:80\n\t"
            "global_load_dwordx4 %6, %16, off offset:96\n\t"
            "global_load_dwordx4 %7, %16, off offset:112\n\t"
            "global_load_dwordx4 %8, %16, off offset:128\n\t"
            "global_load_dwordx4 %9, %16, off offset:144\n\t"
            "global_load_dwordx4 %10, %16, off offset:160\n\t"
            "global_load_dwordx4 %11, %16, off offset:176\n\t"
            "global_load_dwordx4 %12, %16, off offset:192\n\t"
            "global_load_dwordx4 %13, %16, off offset:208\n\t"
            "global_load_dwordx4 %14, %16, off offset:224\n\t"
            "global_load_dwordx4 %15, %16, off offset:240\n\t"
            "s_waitcnt vmcnt(0)"
            : "=&v"(W00), "=&v"(W01), "=&v"(W02), "=&v"(W03),
              "=&v"(W04), "=&v"(W05), "=&v"(W06), "=&v"(W07),
              "=&v"(W08), "=&v"(W09), "=&v"(W10), "=&v"(W11),
              "=&v"(W12), "=&v"(W13), "=&v"(W14), "=&v"(W15)
            : "v"(wp));
        asm volatile(
            "global_load_dwordx4 %0, %16, off offset:256\n\t"
            "global_load_dwordx4 %1, %16, off offset:272\n\t"
            "global_load_dwordx4 %2, %16, off offset:288\n\t"
            "global_load_dwordx4 %3, %16, off offset:304\n\t"
            "global_load_dwordx4 %4, %16, off offset:320\n\t"
            "global_load_dwordx4 %5, %16, off offset:336\n\t"
            "global_load_dwordx4 %6, %16, off offset:352\n\t"
            "global_load_dwordx4 %7, %16, off offset:368\n\t"
            "global_load_dwordx4 %8, %16, off offset:384\n\t"
            "global_load_dwordx4 %9, %16, off offset:400\n\t"
            "global_load_dwordx4 %10, %16, off offset:416\n\t"
            "global_load_dwordx4 %11, %16, off offset:432\n\t"
            "global_load_dwordx4 %12, %16, off offset:448\n\t"
            "global_load_dwordx4 %13, %16, off offset:464\n\t"
            "global_load_dwordx4 %14, %16, off offset:480\n\t"
            "global_load_dwordx4 %15, %16, off offset:496\n\t"
            "s_waitcnt vmcnt(0)"
            : "=&v"(W16), "=&v"(W17), "=&v"(W18), "=&v"(W19),
              "=&v"(W20), "=&v"(W21), "=&v"(W22), "=&v"(W23),
              "=&v"(W24), "=&v"(W25), "=&v"(W26), "=&v"(W27),
              "=&v"(W28), "=&v"(W29), "=&v"(W30), "=&v"(W31)
            : "v"(wp));
        asm volatile(
            "global_load_dwordx4 %0, %16, off offset:512\n\t"
            "global_load_dwordx4 %1, %16, off offset:528\n\t"
            "global_load_dwordx4 %2, %16, off offset:544\n\t"
            "global_load_dwordx4 %3, %16, off offset:560\n\t"
            "global_load_dwordx4 %4, %16, off offset:576\n\t"
            "global_load_dwordx4 %5, %16, off offset:592\n\t"
            "global_load_dwordx4 %6, %16, off offset:608\n\t"
            "global_load_dwordx4 %7, %16, off offset:624\n\t"
            "global_load_dwordx4 %8, %16, off offset:640\n\t"
            "global_load_dwordx4 %9, %16, off offset:656\n\t"
            "global_load_dwordx4 %10, %16, off offset:672\n\t"
            "global_load_dwordx4 %11, %16, off offset:688\n\t"
            "global_load_dwordx4 %12, %16, off offset:704\n\t"
            "global_load_dwordx4 %13, %16, off offset:720\n\t"
            "global_load_dwordx4 %14, %16, off offset:736\n\t"
            "global_load_dwordx4 %15, %16, off offset:752\n\t"
            "s_waitcnt vmcnt(0)"
            : "=&v"(W32), "=&v"(W33), "=&v"(W34), "=&v"(W35),
              "=&v"(W36), "=&v"(W37), "=&v"(W38), "=&v"(W39),
              "=&v"(W40), "=&v"(W41), "=&v"(W42), "=&v"(W43),
              "=&v"(W44), "=&v"(W45), "=&v"(W46), "=&v"(W47)
            : "v"(wp));
        asm volatile(
            "global_load_dwordx4 %0, %16, off offset:768\n\t"
            "global_load_dwordx4 %1, %16, off offset:784\n\t"
            "global_load_dwordx4 %2, %16, off offset:800\n\t"
            "global_load_dwordx4 %3, %16, off offset:816\n\t"
            "global_load_dwordx4 %4, %16, off offset:832\n\t"
            "global_load_dwordx4 %5, %16, off offset:848\n\t"
            "global_load_dwordx4 %6, %16, off offset:864\n\t"
            "global_load_dwordx4 %7, %16, off offset:880\n\t"
            "global_load_dwordx4 %8, %16, off offset:896\n\t"
            "global_load_dwordx4 %9, %16, off offset:912\n\t"
            "global_load_dwordx4 %10, %16, off offset:928\n\t"
            "global_load_dwordx4 %11, %16, off offset:944\n\t"
            "global_load_dwordx4 %12, %16, off offset:960\n\t"
            "global_load_dwordx4 %13, %16, off offset:976\n\t"
            "global_load_dwordx4 %14, %16, off offset:992\n\t"
            "global_load_dwordx4 %15, %16, off offset:1008\n\t"
            "s_waitcnt vmcnt(0)"
            : "=&v"(W48), "=&v"(W49), "=&v"(W50), "=&v"(W51),
              "=&v"(W52), "=&v"(W53), "=&v"(W54), "=&v"(W55),
              "=&v"(W56), "=&v"(W57), "=&v"(W58), "=&v"(W59),
              "=&v"(W60), "=&v"(W61), "=&v"(W62), "=&v"(W63)
            : "v"(wp));
    }

    const float4 wsc4 = *(const float4*)(g_wscale + 4 * t);   // scales: gates i,f,g,o of unit t
    float c_reg = ldin(mode, c0, (size_t)b * H_ + t);

    if (t < H_ / 4) {
        u32 pk = 0;
#pragma unroll
        for (int i = 0; i < 4; ++i) {
            float h = ldin(mode, h0, (size_t)b * H_ + 4 * t + i);
            int q = (int)rintf(fminf(fmaxf(h, -1.0f), 1.0f) * 127.0f);
            pk |= ((u32)(q & 0xff)) << (8 * i);
        }
        h8[0][t] = pk;
    }
    const u16* xp = g_xg + (size_t)b * S_ * G_ + 4 * t;
    float* hsp = g_hs + (size_t)b * S_ * H_ + t;
    ushort4 xv = *(const ushort4*)xp;
    __syncthreads();

    for (int s = 0; s < S_; ++s) {
        size_t nxt = (size_t)((s + 1 < S_) ? (s + 1) : s) * G_;
        ushort4 xv_n = *(const ushort4*)(xp + nxt);   // prefetch next step's xg

        const uint4* hp = (const uint4*)h8[s & 1];
        uint4 h0v = hp[0], h1v = hp[1], h2v = hp[2], h3v = hp[3];
        uint4 h4v = hp[4], h5v = hp[5], h6v = hp[6], h7v = hp[7];
        uint4 h8v = hp[8], h9v = hp[9], h10v = hp[10], h11v = hp[11];
        uint4 h12v = hp[12], h13v = hp[13], h14v = hp[14], h15v = hp[15];

        int ai = 0, af = 0, ag = 0, ao = 0;
#define DOTG(HV, WA, WB, WC, WD)                                              \
        ai = dot4i8(HV.x, WA.x, ai); af = dot4i8(HV.x, WA.y, af);             \
        ag = dot4i8(HV.x, WA.z, ag); ao = dot4i8(HV.x, WA.w, ao);             \
        ai = dot4i8(HV.y, WB.x, ai); af = dot4i8(HV.y, WB.y, af);             \
        ag = dot4i8(HV.y, WB.z, ag); ao = dot4i8(HV.y, WB.w, ao);             \
        ai = dot4i8(HV.z, WC.x, ai); af = dot4i8(HV.z, WC.y, af);             \
        ag = dot4i8(HV.z, WC.z, ag); ao = dot4i8(HV.z, WC.w, ao);             \
        ai = dot4i8(HV.w, WD.x, ai); af = dot4i8(HV.w, WD.y, af);             \
        ag = dot4i8(HV.w, WD.z, ag); ao = dot4i8(HV.w, WD.w, ao);
        DOTG(h0v,  W00, W01, W02, W03)
        DOTG(h1v,  W04, W05, W06, W07)
        DOTG(h2v,  W08, W09, W10, W11)
        DOTG(h3v,  W12, W13, W14, W15)
        DOTG(h4v,  W16, W17, W18, W19)
        DOTG(h5v,  W20, W21, W22, W23)
        DOTG(h6v,  W24, W25, W26, W27)
        DOTG(h7v,  W28, W29, W30, W31)
        DOTG(h8v,  W32, W33, W34, W35)
        DOTG(h9v,  W36, W37, W38, W39)
        DOTG(h10v, W40, W41, W42, W43)
        DOTG(h11v, W44, W45, W46, W47)
        DOTG(h12v, W48, W49, W50, W51)
        DOTG(h13v, W52, W53, W54, W55)
        DOTG(h14v, W56, W57, W58, W59)
        DOTG(h15v, W60, W61, W62, W63)
#undef DOTG

        float gi = (float)ai * wsc4.x + b2f(xv.x);
        float gf = (float)af * wsc4.y + b2f(xv.y);
        float gg = (float)ag * wsc4.z + b2f(xv.z);
        float go = (float)ao * wsc4.w + b2f(xv.w);
        float ii = sigmoidf_(clamp30(gi));
        float ff = sigmoidf_(clamp30(gf));
        float gv = tanhf_(clamp30(gg));
        float oo = sigmoidf_(clamp30(go));
        c_reg = fmaf(ff, c_reg, ii * gv);
        float h = oo * tanhf_(c_reg);

        hsp[(size_t)s * H_] = h;                 // fp32 h stream for the output head

        int q = (int)rintf(fminf(fmaxf(h, -1.0f), 1.0f) * 127.0f) & 0xff;
        int q1 = __shfl_down(q, 1, 64);
        int q2 = __shfl_down(q, 2, 64);
        int q3 = __shfl_down(q, 3, 64);
        if ((t & 3) == 0)
            h8[(s + 1) & 1][t >> 2] = (u32)q | ((u32)q1 << 8) | ((u32)q2 << 16) | ((u32)q3 << 24);
        xv = xv_n;
        __syncthreads();                         // writes visible; prior-buffer reads done
    }
}

// ---------- K3: output head — one wave per (s,b), fp32 h ----------
__global__ __launch_bounds__(256) void head_kernel(const void* __restrict__ Wout,
                                                   const void* __restrict__ bout,
                                                   void* __restrict__ yv) {
    const int mode = g_mode;
    const int t = threadIdx.x;
    const int idx = blockIdx.x * 4 + (t >> 6);   // (s,b) pair
    const int l = t & 63;
    const int s = idx >> 6, b = idx & 63;
    const float* hb = g_hs + ((size_t)b * S_ + s) * H_ + 4 * l;
    float4 hv = *(const float4*)hb;
    float p = hv.x * ldin(mode, Wout, 4 * l + 0)
            + hv.y * ldin(mode, Wout, 4 * l + 1)
            + hv.z * ldin(mode, Wout, 4 * l + 2)
            + hv.w * ldin(mode, Wout, 4 * l + 3);
#pragma unroll
    for (int off = 32; off > 0; off >>= 1) p += __shfl_down(p, off, 64);
    if (l == 0) {
        float yf = sigmoidf_(clamp30(p + ldin(mode, bout, 0)));
        if (mode) ((float*)yv)[(size_t)s * B_ + b] = yf;
        else      ((u16*)yv)[(size_t)s * B_ + b] = f2b(yf);
    }
}

extern "C" void kernel_launch(void* const* d_in, const int* in_sizes, int n_in,
                              void* d_out, int out_size, void* d_ws, size_t ws_size,
                              hipStream_t stream) {
    const void* pw   = d_in[0];   // [B,S,50]
    const void* Wemb = d_in[1];   // [E,50]
    const void* bemb = d_in[2];   // [E]
    const void* Wih  = d_in[3];   // [G,E]
    const void* Whh  = d_in[4];   // [G,H]
    const void* bih  = d_in[5];   // [G]
    const void* bhh  = d_in[6];   // [G]
    const void* Wout = d_in[7];   // [1,H]
    const void* bout = d_in[8];   // [1]
    const void* h0   = d_in[9];   // [B,H]
    const void* c0   = d_in[10];  // [B,H]
    void* y = d_out;              // [S,B]
    (void)d_ws; (void)ws_size;

    sniff_kernel<<<1, 1, 0, stream>>>((const u16*)Wemb);
    transpose_wih<<<(E_ * G_) / 256, 256, 0, stream>>>(Wih);
    prep_wi8<<<G_ / 256, 256, 0, stream>>>(Whh);
    xg_kernel<<<(B_ * S_) / 16, 256, 0, stream>>>(pw, Wemb, bemb, bih, bhh);
    lstm_unit<<<B_, 256, 0, stream>>>(h0, c0);
    head_kernel<<<(S_ * B_) / 4, 256, 0, stream>>>(Wout, bout, y);
}

// Round 13
// 3069.939 us; speedup vs baseline: 1.3148x; 1.3148x over previous
//
#include <hip/hip_runtime.h>
#include <hip/hip_bf16.h>

// B=64, S=2048, WIN=50, E=128, H=256, G=4H=1024.
#define B_ 64
#define S_ 2048
#define W_ 50
#define E_ 128
#define H_ 256
#define G_ 1024

typedef unsigned short u16;
typedef unsigned int u32;
typedef unsigned int v4u __attribute__((ext_vector_type(4)));

// Module-global scratch (BSS; d_ws untrusted).
__device__ int g_mode;                          // 0 = bf16 buffers, 1 = fp32 buffers
__device__ u16 g_WihT[E_ * G_];                 // [e][4u+q] = Wih[q*H+u][e]  (bf16)
__device__ u32 g_Wi8[G_ * 64];                  // [u][j][g]: u*256+j*4+g = pack4(Whh[g*256+u][4j..4j+3])
__device__ float g_wscale[G_];                  // per-column dequant: max|W[:,c]| /(127*127), c=4u+g
__device__ u16 g_xg[(size_t)B_ * S_ * G_];      // [b][s][1024] bf16, biases folded (validated)
__device__ float g_hs[(size_t)B_ * S_ * H_];    // [b][s][u] fp32 hidden states (for output head)

__device__ __forceinline__ float b2f(u16 u) {
    union { u32 i; float f; } v;
    v.i = ((u32)u) << 16;
    return v.f;
}
__device__ __forceinline__ u16 f2b(float f) {
    __hip_bfloat16 h = __float2bfloat16(f);
    return *reinterpret_cast<u16*>(&h);
}
__device__ __forceinline__ float ldin(int mode, const void* p, size_t i) {
    return mode ? ((const float*)p)[i] : b2f(((const u16*)p)[i]);
}
__device__ __forceinline__ float clamp30(float x) {
    return fminf(fmaxf(x, -30.0f), 30.0f);
}
__device__ __forceinline__ float sigmoidf_(float x) { return 1.0f / (1.0f + __expf(-x)); }
__device__ __forceinline__ float tanhf_(float x) {
    float e = __expf(2.0f * x);
    return 1.0f - 2.0f / (e + 1.0f);
}
__device__ __forceinline__ int dot4i8(u32 a, u32 b, int acc) {
#if __has_builtin(__builtin_amdgcn_sdot4)
    return __builtin_amdgcn_sdot4(a, b, acc, false);
#else
    acc += (int)(signed char)(a)       * (int)(signed char)(b);
    acc += (int)(signed char)(a >> 8)  * (int)(signed char)(b >> 8);
    acc += (int)(signed char)(a >> 16) * (int)(signed char)(b >> 16);
    acc += (int)(signed char)(a >> 24) * (int)(signed char)(b >> 24);
    return acc;
#endif
}

// ---------- K0: dtype sniffer (validated) ----------
__global__ void sniff_kernel(const u16* __restrict__ wemb) {
    int sane = 0;
    for (int i = 0; i < 2048; ++i) {
        int ex = (wemb[i] >> 7) & 0xFF;
        if (ex == 0 || (ex >= 96 && ex <= 143)) ++sane;
    }
    g_mode = (sane >= 1900) ? 0 : 1;
}

// ---------- K0b: Wih gate-interleaved transpose (for xg_kernel) ----------
__global__ __launch_bounds__(256) void transpose_wih(const void* __restrict__ src) {
    const int mode = g_mode;
    int i = blockIdx.x * 256 + threadIdx.x;          // i = e*G + 4u+q
    int e = i >> 10, r = i & 1023, u = r >> 2, q = r & 3;
    g_WihT[i] = f2b(ldin(mode, src, (size_t)((q << 15) + (u << 7) + e)));
}

// ---------- K0c: Whh -> int8, unit-major quad layout [u][j][g] (validated) ----------
__global__ __launch_bounds__(256) void prep_wi8(const void* __restrict__ src) {
    const int mode = g_mode;
    int c = blockIdx.x * 256 + threadIdx.x;          // c = 4u+g, 0..1023
    int row = ((c & 3) << 8) + (c >> 2);             // gate*256 + unit (validated)
    const size_t base = (size_t)row * H_;
    float m = 0.0f;
    for (int k = 0; k < H_; ++k) m = fmaxf(m, fabsf(ldin(mode, src, base + k)));
    float inv = (m > 0.0f) ? 127.0f / m : 0.0f;
    g_wscale[c] = m / (127.0f * 127.0f);             // w-scale * h-scale(1/127)
    for (int j = 0; j < 64; ++j) {
        u32 pk = 0;
#pragma unroll
        for (int i = 0; i < 4; ++i) {
            int q = (int)rintf(ldin(mode, src, base + 4 * j + i) * inv);
            q = max(-127, min(127, q));
            pk |= ((u32)(q & 0xff)) << (8 * i);
        }
        g_Wi8[(size_t)(c >> 2) * 256 + j * 4 + (c & 3)] = pk;
    }
}

// ---------- K1: fused embedding + input projection (validated round 4) ----------
__global__ __launch_bounds__(256) void xg_kernel(const void* __restrict__ pw,
                                                 const void* __restrict__ Wemb,
                                                 const void* __restrict__ bemb,
                                                 const void* __restrict__ bih,
                                                 const void* __restrict__ bhh) {
    const int mode = g_mode;
    const int t = threadIdx.x;
    const int m0 = blockIdx.x * 16;
    __shared__ float pw16[16][W_ + 2];
    __shared__ float Wl[E_ * 51];
    __shared__ __align__(16) float erow[16][E_];

    for (int i = t; i < E_ * W_; i += 256) {
        int e = i / W_, w = i - e * W_;
        Wl[e * 51 + w] = ldin(mode, Wemb, i);
    }
    for (int i = t; i < 16 * W_; i += 256) {
        int r = i / W_, w = i - r * W_;
        pw16[r][w] = ldin(mode, pw, (size_t)(m0 + r) * W_ + w);
    }
    __syncthreads();

#pragma unroll
    for (int i = 0; i < 8; ++i) {
        int idx = i * 256 + t;
        int r = idx >> 7, e = idx & 127;
        float a = ldin(mode, bemb, e);
        const float* wr = &Wl[e * 51];
#pragma unroll
        for (int w = 0; w < W_; ++w) a = fmaf(pw16[r][w], wr[w], a);
        erow[r][e] = fmaxf(a, 0.0f);
    }
    __syncthreads();

    const int g0 = 4 * t;
    float acc[16][4];
    {
        float b0 = ldin(mode, bih, t) + ldin(mode, bhh, t);
        float b1 = ldin(mode, bih, H_ + t) + ldin(mode, bhh, H_ + t);
        float b2 = ldin(mode, bih, 2 * H_ + t) + ldin(mode, bhh, 2 * H_ + t);
        float b3 = ldin(mode, bih, 3 * H_ + t) + ldin(mode, bhh, 3 * H_ + t);
#pragma unroll
        for (int r = 0; r < 16; ++r) { acc[r][0] = b0; acc[r][1] = b1; acc[r][2] = b2; acc[r][3] = b3; }
    }
    for (int e = 0; e < E_; e += 4) {
        ushort4 w0 = *(const ushort4*)(g_WihT + (size_t)(e + 0) * G_ + g0);
        ushort4 w1 = *(const ushort4*)(g_WihT + (size_t)(e + 1) * G_ + g0);
        ushort4 w2 = *(const ushort4*)(g_WihT + (size_t)(e + 2) * G_ + g0);
        ushort4 w3 = *(const ushort4*)(g_WihT + (size_t)(e + 3) * G_ + g0);
        float f00 = b2f(w0.x), f01 = b2f(w0.y), f02 = b2f(w0.z), f03 = b2f(w0.w);
        float f10 = b2f(w1.x), f11 = b2f(w1.y), f12 = b2f(w1.z), f13 = b2f(w1.w);
        float f20 = b2f(w2.x), f21 = b2f(w2.y), f22 = b2f(w2.z), f23 = b2f(w2.w);
        float f30 = b2f(w3.x), f31 = b2f(w3.y), f32 = b2f(w3.z), f33 = b2f(w3.w);
#pragma unroll
        for (int r = 0; r < 16; ++r) {
            float4 ev = *(const float4*)&erow[r][e];
            acc[r][0] = fmaf(ev.x, f00, acc[r][0]); acc[r][1] = fmaf(ev.x, f01, acc[r][1]);
            acc[r][2] = fmaf(ev.x, f02, acc[r][2]); acc[r][3] = fmaf(ev.x, f03, acc[r][3]);
            acc[r][0] = fmaf(ev.y, f10, acc[r][0]); acc[r][1] = fmaf(ev.y, f11, acc[r][1]);
            acc[r][2] = fmaf(ev.y, f12, acc[r][2]); acc[r][3] = fmaf(ev.y, f13, acc[r][3]);
            acc[r][0] = fmaf(ev.z, f20, acc[r][0]); acc[r][1] = fmaf(ev.z, f21, acc[r][1]);
            acc[r][2] = fmaf(ev.z, f22, acc[r][2]); acc[r][3] = fmaf(ev.z, f23, acc[r][3]);
            acc[r][0] = fmaf(ev.w, f30, acc[r][0]); acc[r][1] = fmaf(ev.w, f31, acc[r][1]);
            acc[r][2] = fmaf(ev.w, f32, acc[r][2]); acc[r][3] = fmaf(ev.w, f33, acc[r][3]);
        }
    }
#pragma unroll
    for (int r = 0; r < 16; ++r) {
        ushort4 sv;
        sv.x = f2b(acc[r][0]); sv.y = f2b(acc[r][1]);
        sv.z = f2b(acc[r][2]); sv.w = f2b(acc[r][3]);
        *(ushort4*)(g_xg + (size_t)(m0 + r) * G_ + g0) = sv;
    }
}

// ---------- K2: recurrence, split-K pairs (512 thr, 8 waves), epoch-chunked I/O ----------
// Thread t = (unit u = t>>1, half = t&1); holds 32 weight quads (128 VGPRs) for k-range
// [half*128, half*128+128). Halves combine via shfl_xor(1) (pair always in same wave).
// xg loaded 8 steps at a time into registers; h stored 8 steps at a time (amortized drains).
__global__ __launch_bounds__(512)
__attribute__((amdgpu_waves_per_eu(2, 2)))
void lstm_split(const void* __restrict__ h0, const void* __restrict__ c0) {
    const int mode = g_mode;
    const int t = threadIdx.x;
    const int b = blockIdx.x;
    const int u = t >> 1;
    const int half = t & 1;

    __shared__ __align__(16) u32 h8[2][H_ / 4];  // double-buffered h (i8), 2x256 B

    // --- 32 weight quads into named v4u via asm (validated pattern, waitcnt per block) ---
    v4u W00, W01, W02, W03, W04, W05, W06, W07, W08, W09, W10, W11, W12, W13, W14, W15;
    v4u W16, W17, W18, W19, W20, W21, W22, W23, W24, W25, W26, W27, W28, W29, W30, W31;
    {
        const u32* wp = g_Wi8 + (size_t)t * 128;   // = u*256 + half*128
        asm volatile(
            "global_load_dwordx4 %0, %16, off\n\t"
            "global_load_dwordx4 %1, %16, off offset:16\n\t"
            "global_load_dwordx4 %2, %16, off offset:32\n\t"
            "global_load_dwordx4 %3, %16, off offset:48\n\t"
            "global_load_dwordx4 %4, %16, off offset:64\n\t"
            "global_load_dwordx4 %5, %16, off offset:80\n\t"
            "global_load_dwordx4 %6, %16, off offset:96\n\t"
            "global_load_dwordx4 %7, %16, off offset:112\n\t"
            "global_load_dwordx4 %8, %16, off offset:128\n\t"
            "global_load_dwordx4 %9, %16, off offset:144\n\t"
            "global_load_dwordx4 %10, %16, off offset:160\n\t"
            "global_load_dwordx4 %11, %16, off offset:176\n\t"
            "global_load_dwordx4 %12, %16, off offset:192\n\t"
            "global_load_dwordx4 %13, %16, off offset:208\n\t"
            "global_load_dwordx4 %14, %16, off offset:224\n\t"
            "global_load_dwordx4 %15, %16, off offset:240\n\t"
            "s_waitcnt vmcnt(0)"
            : "=&v"(W00), "=&v"(W01), "=&v"(W02), "=&v"(W03),
              "=&v"(W04), "=&v"(W05), "=&v"(W06), "=&v"(W07),
              "=&v"(W08), "=&v"(W09), "=&v"(W10), "=&v"(W11),
              "=&v"(W12), "=&v"(W13), "=&v"(W14), "=&v"(W15)
            : "v"(wp));
        asm volatile(
            "global_load_dwordx4 %0, %16, off offset:256\n\t"
            "global_load_dwordx4 %1, %16, off offset:272\n\t"
            "global_load_dwordx4 %2, %16, off offset:288\n\t"
            "global_load_dwordx4 %3, %16, off offset:304\n\t"
            "global_load_dwordx4 %4, %16, off offset:320\n\t"
            "global_load_dwordx4 %5, %16, off offset:336\n\t"
            "global_load_dwordx4 %6, %16, off offset:352\n\t"
            "global_load_dwordx4 %7, %16, off offset:368\n\t"
            "global_load_dwordx4 %8, %16, off offset:384\n\t"
            "global_load_dwordx4 %9, %16, off offset:400\n\t"
            "global_load_dwordx4 %10, %16, off offset:416\n\t"
            "global_load_dwordx4 %11, %16, off offset:432\n\t"
            "global_load_dwordx4 %12, %16, off offset:448\n\t"
            "global_load_dwordx4 %13, %16, off offset:464\n\t"
            "global_load_dwordx4 %14, %16, off offset:480\n\t"
            "global_load_dwordx4 %15, %16, off offset:496\n\t"
            "s_waitcnt vmcnt(0)"
            : "=&v"(W16), "=&v"(W17), "=&v"(W18), "=&v"(W19),
              "=&v"(W20), "=&v"(W21), "=&v"(W22), "=&v"(W23),
              "=&v"(W24), "=&v"(W25), "=&v"(W26), "=&v"(W27),
              "=&v"(W28), "=&v"(W29), "=&v"(W30), "=&v"(W31)
            : "v"(wp));
    }

    const float4 wsc4 = *(const float4*)(g_wscale + 4 * u);
    float c_reg = (half == 0) ? ldin(mode, c0, (size_t)b * H_ + u) : 0.0f;

    if (t < H_ / 4) {
        u32 pk = 0;
#pragma unroll
        for (int i = 0; i < 4; ++i) {
            float h = ldin(mode, h0, (size_t)b * H_ + 4 * t + i);
            int q = (int)rintf(fminf(fmaxf(h, -1.0f), 1.0f) * 127.0f);
            pk |= ((u32)(q & 0xff)) << (8 * i);
        }
        h8[0][t] = pk;
    }
    const u16* xp = g_xg + (size_t)b * S_ * G_ + 4 * u;
    float* hsp = g_hs + (size_t)b * S_ * H_ + u;
    __syncthreads();

    for (int s0 = 0; s0 < S_; s0 += 8) {
        // epoch: load 8 steps of xg into registers (even threads only)
        ushort4 xq[8];
        if (half == 0) {
#pragma unroll
            for (int e = 0; e < 8; ++e)
                xq[e] = *(const ushort4*)(xp + (size_t)(s0 + e) * G_);
        }
        float hbuf[8];

#pragma unroll
        for (int e = 0; e < 8; ++e) {
            const int s = s0 + e;
            // stage my k-half of h (8 broadcast uint4 reads)
            const uint4* hp = (const uint4*)h8[s & 1] + half * 8;
            uint4 h0v = hp[0], h1v = hp[1], h2v = hp[2], h3v = hp[3];
            uint4 h4v = hp[4], h5v = hp[5], h6v = hp[6], h7v = hp[7];

            int ai = 0, af = 0, ag = 0, ao = 0;
#define DOTG(HV, WA, WB, WC, WD)                                              \
            ai = dot4i8(HV.x, WA.x, ai); af = dot4i8(HV.x, WA.y, af);         \
            ag = dot4i8(HV.x, WA.z, ag); ao = dot4i8(HV.x, WA.w, ao);         \
            ai = dot4i8(HV.y, WB.x, ai); af = dot4i8(HV.y, WB.y, af);         \
            ag = dot4i8(HV.y, WB.z, ag); ao = dot4i8(HV.y, WB.w, ao);         \
            ai = dot4i8(HV.z, WC.x, ai); af = dot4i8(HV.z, WC.y, af);         \
            ag = dot4i8(HV.z, WC.z, ag); ao = dot4i8(HV.z, WC.w, ao);         \
            ai = dot4i8(HV.w, WD.x, ai); af = dot4i8(HV.w, WD.y, af);         \
            ag = dot4i8(HV.w, WD.z, ag); ao = dot4i8(HV.w, WD.w, ao);
            DOTG(h0v, W00, W01, W02, W03)
            DOTG(h1v, W04, W05, W06, W07)
            DOTG(h2v, W08, W09, W10, W11)
            DOTG(h3v, W12, W13, W14, W15)
            DOTG(h4v, W16, W17, W18, W19)
            DOTG(h5v, W20, W21, W22, W23)
            DOTG(h6v, W24, W25, W26, W27)
            DOTG(h7v, W28, W29, W30, W31)
#undef DOTG
            // combine halves (pair is lanes 2u,2u+1 — always same wave)
            ai += __shfl_xor(ai, 1, 64);
            af += __shfl_xor(af, 1, 64);
            ag += __shfl_xor(ag, 1, 64);
            ao += __shfl_xor(ao, 1, 64);

            if (half == 0) {
                float gi = (float)ai * wsc4.x + b2f(xq[e].x);
                float gf = (float)af * wsc4.y + b2f(xq[e].y);
                float gg = (float)ag * wsc4.z + b2f(xq[e].z);
                float go = (float)ao * wsc4.w + b2f(xq[e].w);
                float ii = sigmoidf_(clamp30(gi));
                float ff = sigmoidf_(clamp30(gf));
                float gv = tanhf_(clamp30(gg));
                float oo = sigmoidf_(clamp30(go));
                c_reg = fmaf(ff, c_reg, ii * gv);
                float h = oo * tanhf_(c_reg);
                hbuf[e] = h;
                // pack 4 units' h: units 4k..4k+3 live on even lanes 8k,8k+2,8k+4,8k+6
                int q = (int)rintf(fminf(fmaxf(h, -1.0f), 1.0f) * 127.0f) & 0xff;
                int q1 = __shfl_down(q, 2, 64);
                int q2 = __shfl_down(q, 4, 64);
                int q3 = __shfl_down(q, 6, 64);
                if ((t & 7) == 0)
                    h8[(s + 1) & 1][t >> 3] =
                        (u32)q | ((u32)q1 << 8) | ((u32)q2 << 16) | ((u32)q3 << 24);
            }
            __syncthreads();                     // h8[(s+1)&1] visible; reads of h8[s&1] done
        }

        // epoch: store 8 steps of h (even threads; drain amortized at next barrier)
        if (half == 0) {
#pragma unroll
            for (int e = 0; e < 8; ++e) hsp[(size_t)(s0 + e) * H_] = hbuf[e];
        }
    }
}

// ---------- K3: output head — one wave per (s,b), fp32 h ----------
__global__ __launch_bounds__(256) void head_kernel(const void* __restrict__ Wout,
                                                   const void* __restrict__ bout,
                                                   void* __restrict__ yv) {
    const int mode = g_mode;
    const int t = threadIdx.x;
    const int idx = blockIdx.x * 4 + (t >> 6);   // (s,b) pair
    const int l = t & 63;
    const int s = idx >> 6, b = idx & 63;
    const float* hb = g_hs + ((size_t)b * S_ + s) * H_ + 4 * l;
    float4 hv = *(const float4*)hb;
    float p = hv.x * ldin(mode, Wout, 4 * l + 0)
            + hv.y * ldin(mode, Wout, 4 * l + 1)
            + hv.z * ldin(mode, Wout, 4 * l + 2)
            + hv.w * ldin(mode, Wout, 4 * l + 3);
#pragma unroll
    for (int off = 32; off > 0; off >>= 1) p += __shfl_down(p, off, 64);
    if (l == 0) {
        float yf = sigmoidf_(clamp30(p + ldin(mode, bout, 0)));
        if (mode) ((float*)yv)[(size_t)s * B_ + b] = yf;
        else      ((u16*)yv)[(size_t)s * B_ + b] = f2b(yf);
    }
}

extern "C" void kernel_launch(void* const* d_in, const int* in_sizes, int n_in,
                              void* d_out, int out_size, void* d_ws, size_t ws_size,
                              hipStream_t stream) {
    const void* pw   = d_in[0];   // [B,S,50]
    const void* Wemb = d_in[1];   // [E,50]
    const void* bemb = d_in[2];   // [E]
    const void* Wih  = d_in[3];   // [G,E]
    const void* Whh  = d_in[4];   // [G,H]
    const void* bih  = d_in[5];   // [G]
    const void* bhh  = d_in[6];   // [G]
    const void* Wout = d_in[7];   // [1,H]
    const void* bout = d_in[8];   // [1]
    const void* h0   = d_in[9];   // [B,H]
    const void* c0   = d_in[10];  // [B,H]
    void* y = d_out;              // [S,B]
    (void)d_ws; (void)ws_size;

    sniff_kernel<<<1, 1, 0, stream>>>((const u16*)Wemb);
    transpose_wih<<<(E_ * G_) / 256, 256, 0, stream>>>(Wih);
    prep_wi8<<<G_ / 256, 256, 0, stream>>>(Whh);
    xg_kernel<<<(B_ * S_) / 16, 256, 0, stream>>>(pw, Wemb, bemb, bih, bhh);
    lstm_split<<<B_, 512, 0, stream>>>(h0, c0);
    head_kernel<<<(S_ * B_) / 4, 256, 0, stream>>>(Wout, bout, y);
}